// Round 10
// baseline (2051.641 us; speedup 1.0000x reference)
//
#include <hip/hip_runtime.h>

#define NHID    1024
#define BATCH   128
#define LSTEPS  1000
#define DTC     0.042f
#define THETA   1.0f
#define TAUM    20.0f
#define LISTCAP 1032

// lgkm-only barrier: guarantees LDS write visibility across the workgroup
// WITHOUT draining vmcnt -> cache-warming global loads stay in flight.
#define BAR() asm volatile("s_waitcnt lgkmcnt(0)\n\ts_barrier" ::: "memory")

// One block per batch element; thread h owns hidden unit h (16 waves/CU).
// Binary-spike matmuls = sparse row gathers over a combined LDS offset list
// (ascending j -> f32 add order identical to R1/R3/R9). New in R10:
//  - spiking threads speculatively touch their OWN weight row right after
//    the spike decision (before any barrier), warming L1/L2 so the gather's
//    row fetches hit warm cache instead of cold L3. Results are sunk via
//    asm AFTER the consuming gather (keeps loads live, adds no wait).
//  - loop barriers are lgkm-only (warming loads cross them in flight).
__global__ __launch_bounds__(1024) void coesn_sim(
    const float* __restrict__ x,        // (B, L, 1)
    const float* __restrict__ x2h,      // (1, H)
    const float* __restrict__ h2h,      // (H, H)
    const float* __restrict__ bias,     // (H)
    const float* __restrict__ lif2hrf,  // (H, H)
    const float* __restrict__ gamma_,   // (H)
    const float* __restrict__ eps_,     // (H)
    float* __restrict__ out,            // (B, 3H) features
    unsigned int* __restrict__ ws)      // (B, 2) spike counts
{
    const int b    = blockIdx.x;
    const int h    = threadIdx.x;
    const int wv   = h >> 6;
    const int lane = h & 63;
    const int wvs  = __builtin_amdgcn_readfirstlane(wv);

    __shared__ unsigned int Ls[LISTCAP];  // HRF spike row byte-offsets
    __shared__ unsigned int Ll[LISTCAP];  // LIF spike row byte-offsets
    __shared__ int Cs[16], Cl[16];
    __shared__ unsigned int red[16];

    Ls[h] = 0; Ll[h] = 0;                 // stale entries stay in-range forever
    if (h < LISTCAP - 1024) { Ls[1024 + h] = 0; Ll[1024 + h] = 0; }
    if (h < 16) { Cs[h] = 0; Cl[h] = 0; }

    float hy = 0.f, hz = 0.f, v = 0.f, rp = 0.f;
    float hysum = 0.f, hysq = 0.f;
    unsigned int chrf = 0, clif = 0;

    const float g    = gamma_[h];
    const float e    = eps_[h];
    const float bi   = bias[h];
    const float win  = x2h[h];
    const float ref_decay = expf((float)(-0.042 / 0.25));
    const float* xb  = x + (size_t)b * LSTEPS;

    const char* hb = (const char*)h2h     + 4 * (size_t)h;
    const char* lb = (const char*)lif2hrf + 4 * (size_t)h;
    const float* rowL = lif2hrf + (size_t)h * NHID;   // own row (phase-C warming)
    const float* rowH = h2h     + (size_t)h * NHID;   // own row (phase-A warming)

    const unsigned long long below = (1ULL << lane) - 1ULL;
    const int l16 = lane & 15;

    int ns = 0;                 // HRF list length (phase A bound); 0 at t=0
    float xv_next = xb[0];      // x prefetch (one step ahead)
    float wsA = 0.f;            // warming sinks
    float wsC = 0.f;

    __syncthreads();

    for (int t = 0; t < LSTEPS; ++t) {
        // ---- phase A: cur = x*x2h + bias + sum of spiking h2h rows ----
        const float xv = xv_next;
        xv_next = xb[(t + 1 < LSTEPS) ? (t + 1) : t];
        float cur = xv * win + bi;
        for (int k = 0; k < ns; k += 8) {
            const unsigned o0 = Ls[k+0], o1 = Ls[k+1], o2 = Ls[k+2], o3 = Ls[k+3];
            const unsigned o4 = Ls[k+4], o5 = Ls[k+5], o6 = Ls[k+6], o7 = Ls[k+7];
            const float a0 = *(const float*)(hb + o0);
            const float a1 = *(const float*)(hb + o1);
            const float a2 = *(const float*)(hb + o2);
            const float a3 = *(const float*)(hb + o3);
            const float a4 = *(const float*)(hb + o4);
            const float a5 = *(const float*)(hb + o5);
            const float a6 = *(const float*)(hb + o6);
            const float a7 = *(const float*)(hb + o7);
            cur += a0;
            cur += (k+1 < ns) ? a1 : 0.0f;
            cur += (k+2 < ns) ? a2 : 0.0f;
            cur += (k+3 < ns) ? a3 : 0.0f;
            cur += (k+4 < ns) ? a4 : 0.0f;
            cur += (k+5 < ns) ? a5 : 0.0f;
            cur += (k+6 < ns) ? a6 : 0.0f;
            cur += (k+7 < ns) ? a7 : 0.0f;
        }
        // sink for phase-D warming issued last iteration (loads long in flight)
        asm volatile("" :: "v"(wsA));

        // ---- phase B: LIF update + spike + warm own lif2hrf row + list ----
        v = v + DTC * (-v / TAUM + cur);
        const float lsp = (v > THETA) ? 1.f : 0.f;
        v -= lsp * THETA;
        clif += (unsigned)lsp;
        wsC = 0.f;
        if (lsp > 0.5f) {                      // warm row h of lif2hrf (32 lines)
            #pragma unroll
            for (int i = 0; i < 32; ++i) wsC += rowL[i * 32];
        }
        __builtin_amdgcn_sched_barrier(0);     // pin warming issue before ballot
        const unsigned long long balL = __ballot(lsp > 0.5f);
        if (lane == 0) Cl[wv] = (int)__popcll(balL);
        BAR();
        int cv = Cl[l16];
        int incl = cv;
        #pragma unroll
        for (int d = 1; d < 16; d <<= 1) {
            const int tt = __shfl_up(incl, d, 16);
            incl += (l16 >= d) ? tt : 0;
        }
        int nl  = __builtin_amdgcn_readlane(incl, 15);
        int pre = __builtin_amdgcn_readlane(incl - cv, wvs);
        if (lsp > 0.5f) Ll[pre + (int)__popcll(balL & below)] = (unsigned)(h * 4096);
        BAR();

        // ---- phase C: drive = sum of spiking lif2hrf rows ----
        float dr = 0.f;
        for (int k = 0; k < nl; k += 8) {
            const unsigned o0 = Ll[k+0], o1 = Ll[k+1], o2 = Ll[k+2], o3 = Ll[k+3];
            const unsigned o4 = Ll[k+4], o5 = Ll[k+5], o6 = Ll[k+6], o7 = Ll[k+7];
            const float a0 = *(const float*)(lb + o0);
            const float a1 = *(const float*)(lb + o1);
            const float a2 = *(const float*)(lb + o2);
            const float a3 = *(const float*)(lb + o3);
            const float a4 = *(const float*)(lb + o4);
            const float a5 = *(const float*)(lb + o5);
            const float a6 = *(const float*)(lb + o6);
            const float a7 = *(const float*)(lb + o7);
            dr += a0;
            dr += (k+1 < nl) ? a1 : 0.0f;
            dr += (k+2 < nl) ? a2 : 0.0f;
            dr += (k+3 < nl) ? a3 : 0.0f;
            dr += (k+4 < nl) ? a4 : 0.0f;
            dr += (k+5 < nl) ? a5 : 0.0f;
            dr += (k+6 < nl) ? a6 : 0.0f;
            dr += (k+7 < nl) ? a7 : 0.0f;
        }
        asm volatile("" :: "v"(wsC));          // sink phase-B warming

        // ---- phase D: HRF update + spike + warm own h2h row + stats + list ----
        hz = hz + DTC * (dr - g * hy - e * hz);
        hy = hy + DTC * hz;
        const float sn = ((hy - THETA - rp) > 0.f) ? 1.f : 0.f;
        rp = rp * ref_decay + sn;
        hysum += hy;
        hysq  += hy * hy;
        chrf += (unsigned)sn;
        wsA = 0.f;
        if (sn > 0.5f) {                       // warm row h of h2h (32 lines)
            #pragma unroll
            for (int i = 0; i < 32; ++i) wsA += rowH[i * 32];
        }
        __builtin_amdgcn_sched_barrier(0);
        const unsigned long long balS = __ballot(sn > 0.5f);
        if (lane == 0) Cs[wv] = (int)__popcll(balS);
        BAR();
        cv = Cs[l16];
        incl = cv;
        #pragma unroll
        for (int d = 1; d < 16; d <<= 1) {
            const int tt = __shfl_up(incl, d, 16);
            incl += (l16 >= d) ? tt : 0;
        }
        ns  = __builtin_amdgcn_readlane(incl, 15);
        pre = __builtin_amdgcn_readlane(incl - cv, wvs);
        if (sn > 0.5f) Ls[pre + (int)__popcll(balS & below)] = (unsigned)(h * 4096);
        BAR();
    }

    // ---- epilogue: features ----
    const float Lf   = (float)LSTEPS;
    const float mean = hysum / Lf;
    const float rms  = sqrtf(hysq / Lf + 1e-8f);
    float var = hysq / Lf - mean * mean;
    var = fmaxf(var, 1e-8f);
    float* ob = out + (size_t)b * (3 * NHID);
    ob[h]            = rms;
    ob[NHID + h]     = sqrtf(var);
    ob[2 * NHID + h] = hy;

    // ---- spike-count reduction (exact ints) ----
    unsigned int c = chrf;
    for (int off = 32; off > 0; off >>= 1) c += __shfl_down(c, off, 64);
    if (lane == 0) red[wv] = c;
    __syncthreads();
    if (h == 0) {
        unsigned int tot = 0;
        for (int i = 0; i < 16; ++i) tot += red[i];
        ws[b * 2] = tot;
    }
    __syncthreads();
    c = clif;
    for (int off = 32; off > 0; off >>= 1) c += __shfl_down(c, off, 64);
    if (lane == 0) red[wv] = c;
    __syncthreads();
    if (h == 0) {
        unsigned int tot = 0;
        for (int i = 0; i < 16; ++i) tot += red[i];
        ws[b * 2 + 1] = tot;
    }
}

__global__ void coesn_final(const unsigned int* __restrict__ ws,
                            float* __restrict__ out)
{
    if (threadIdx.x == 0 && blockIdx.x == 0) {
        unsigned long long hrf = 0, lif = 0;
        for (int b = 0; b < BATCH; ++b) {
            hrf += ws[b * 2];
            lif += ws[b * 2 + 1];
        }
        const float denom = (float)BATCH * (float)LSTEPS * (float)NHID;
        const float r_hrf = (float)hrf / denom;
        const float r_lif = (float)lif / denom;
        float* s = out + (size_t)BATCH * 3 * NHID;
        s[0] = r_hrf;
        s[1] = r_hrf;
        s[2] = r_lif;
    }
}

extern "C" void kernel_launch(void* const* d_in, const int* in_sizes, int n_in,
                              void* d_out, int out_size, void* d_ws, size_t ws_size,
                              hipStream_t stream) {
    const float* x       = (const float*)d_in[0];
    const float* x2h     = (const float*)d_in[1];
    const float* h2h     = (const float*)d_in[2];
    const float* bias    = (const float*)d_in[3];
    const float* lif2hrf = (const float*)d_in[4];
    const float* gamma_  = (const float*)d_in[5];
    const float* eps_    = (const float*)d_in[6];
    float* out = (float*)d_out;
    unsigned int* wsp = (unsigned int*)d_ws;

    coesn_sim<<<BATCH, NHID, 0, stream>>>(x, x2h, h2h, bias, lif2hrf, gamma_, eps_, out, wsp);
    coesn_final<<<1, 64, 0, stream>>>(wsp, out);
}

// Round 11
// 1724.166 us; speedup vs baseline: 1.1899x; 1.1899x over previous
//
#include <hip/hip_runtime.h>

#define NHID    1024
#define BATCH   128
#define LSTEPS  1000
#define DTC     0.042f
#define THETA   1.0f
#define TAUM    20.0f
#define NT      512
#define LISTCAP 1032

// One block per batch element; 512 threads, thread t owns ADJACENT units
// (2t, 2t+1) -> each spiking-row gather load is a float2 (8B/lane): same
// bytes, HALF the vector-memory instructions of the R9 kernel (the theory
// under test: TA/L1 instruction-throughput is the unexplained ~1000 cyc/step).
// List build and scan are R9's, narrowed to 8 waves. Per-unit accumulation
// order is strictly ascending row index -> bit-identical numerics.
__global__ __launch_bounds__(NT) void coesn_sim(
    const float* __restrict__ x,        // (B, L, 1)
    const float* __restrict__ x2h,      // (1, H)
    const float* __restrict__ h2h,      // (H, H)
    const float* __restrict__ bias,     // (H)
    const float* __restrict__ lif2hrf,  // (H, H)
    const float* __restrict__ gamma_,   // (H)
    const float* __restrict__ eps_,     // (H)
    float* __restrict__ out,            // (B, 3H) features
    unsigned int* __restrict__ ws)      // (B, 2) spike counts
{
    const int b    = blockIdx.x;
    const int tid  = threadIdx.x;
    const int wv   = tid >> 6;          // 0..7
    const int lane = tid & 63;
    const int wvs  = __builtin_amdgcn_readfirstlane(wv);
    const int l8   = lane & 7;

    __shared__ unsigned int Ls[LISTCAP];  // HRF spike row byte-offsets
    __shared__ unsigned int Ll[LISTCAP];  // LIF spike row byte-offsets
    __shared__ int Cs[8], Cl[8];
    __shared__ unsigned int red[8];

    Ls[tid] = 0; Ls[tid + 512] = 0;       // stale entries stay in-range forever
    Ll[tid] = 0; Ll[tid + 512] = 0;
    if (tid < LISTCAP - 1024) { Ls[1024 + tid] = 0; Ll[1024 + tid] = 0; }
    if (tid < 8) { Cs[tid] = 0; Cl[tid] = 0; }

    const int u0 = 2 * tid;               // even unit; u0+1 is the odd partner
    const float2 gg = *(const float2*)(gamma_ + u0);
    const float2 ee = *(const float2*)(eps_  + u0);
    const float2 bb = *(const float2*)(bias  + u0);
    const float2 ww = *(const float2*)(x2h   + u0);
    const float ref_decay = expf((float)(-0.042 / 0.25));
    const float* xb = x + (size_t)b * LSTEPS;

    const char* hb = (const char*)h2h     + 8 * (size_t)tid;   // cols 2t,2t+1
    const char* lb = (const char*)lif2hrf + 8 * (size_t)tid;

    float hy0 = 0.f, hy1 = 0.f, hz0 = 0.f, hz1 = 0.f;
    float v0 = 0.f, v1 = 0.f, rp0 = 0.f, rp1 = 0.f;
    float hysum0 = 0.f, hysum1 = 0.f, hysq0 = 0.f, hysq1 = 0.f;
    unsigned int chrf = 0, clif = 0;

    const unsigned long long below = (1ULL << lane) - 1ULL;

    int ns = 0;                 // HRF list length; 0 at t=0
    float xv_next = xb[0];      // x prefetch (one step ahead)

    __syncthreads();

    for (int t = 0; t < LSTEPS; ++t) {
        // ---- phase A: cur = x*x2h + bias + sum of spiking h2h rows ----
        const float xv = xv_next;
        xv_next = xb[(t + 1 < LSTEPS) ? (t + 1) : t];
        float c0 = xv * ww.x + bb.x;
        float c1 = xv * ww.y + bb.y;
        for (int k = 0; k < ns; k += 8) {
            const unsigned o0 = Ls[k+0], o1 = Ls[k+1], o2 = Ls[k+2], o3 = Ls[k+3];
            const unsigned o4 = Ls[k+4], o5 = Ls[k+5], o6 = Ls[k+6], o7 = Ls[k+7];
            const float2 a0 = *(const float2*)(hb + o0);
            const float2 a1 = *(const float2*)(hb + o1);
            const float2 a2 = *(const float2*)(hb + o2);
            const float2 a3 = *(const float2*)(hb + o3);
            const float2 a4 = *(const float2*)(hb + o4);
            const float2 a5 = *(const float2*)(hb + o5);
            const float2 a6 = *(const float2*)(hb + o6);
            const float2 a7 = *(const float2*)(hb + o7);
            c0 += a0.x;                         c1 += a0.y;
            c0 += (k+1 < ns) ? a1.x : 0.0f;     c1 += (k+1 < ns) ? a1.y : 0.0f;
            c0 += (k+2 < ns) ? a2.x : 0.0f;     c1 += (k+2 < ns) ? a2.y : 0.0f;
            c0 += (k+3 < ns) ? a3.x : 0.0f;     c1 += (k+3 < ns) ? a3.y : 0.0f;
            c0 += (k+4 < ns) ? a4.x : 0.0f;     c1 += (k+4 < ns) ? a4.y : 0.0f;
            c0 += (k+5 < ns) ? a5.x : 0.0f;     c1 += (k+5 < ns) ? a5.y : 0.0f;
            c0 += (k+6 < ns) ? a6.x : 0.0f;     c1 += (k+6 < ns) ? a6.y : 0.0f;
            c0 += (k+7 < ns) ? a7.x : 0.0f;     c1 += (k+7 < ns) ? a7.y : 0.0f;
        }

        // ---- phase B: LIF update + spikes + list build ----
        v0 = v0 + DTC * (-v0 / TAUM + c0);
        v1 = v1 + DTC * (-v1 / TAUM + c1);
        const float lsp0 = (v0 > THETA) ? 1.f : 0.f;
        const float lsp1 = (v1 > THETA) ? 1.f : 0.f;
        v0 -= lsp0 * THETA;
        v1 -= lsp1 * THETA;
        clif += (unsigned)lsp0 + (unsigned)lsp1;
        const unsigned long long bA = __ballot(lsp0 > 0.5f);
        const unsigned long long bB = __ballot(lsp1 > 0.5f);
        if (lane == 0) Cl[wv] = (int)(__popcll(bA) + __popcll(bB));
        __syncthreads();
        int cv = Cl[l8];
        int incl = cv;
        #pragma unroll
        for (int d = 1; d < 8; d <<= 1) {
            const int tt = __shfl_up(incl, d, 8);
            incl += (l8 >= d) ? tt : 0;
        }
        int nl  = __builtin_amdgcn_readlane(incl, 7);
        int pre = __builtin_amdgcn_readlane(incl - cv, wvs);
        {
            const int posA = (int)(__popcll(bA & below) + __popcll(bB & below));
            if (lsp0 > 0.5f) Ll[pre + posA] = (unsigned)(u0 * 4096);
            if (lsp1 > 0.5f)
                Ll[pre + posA + (int)((bA >> lane) & 1ULL)] = (unsigned)(u0 * 4096 + 4096);
        }
        __syncthreads();

        // ---- phase C: drive = sum of spiking lif2hrf rows ----
        float d0 = 0.f, d1 = 0.f;
        for (int k = 0; k < nl; k += 8) {
            const unsigned o0 = Ll[k+0], o1 = Ll[k+1], o2 = Ll[k+2], o3 = Ll[k+3];
            const unsigned o4 = Ll[k+4], o5 = Ll[k+5], o6 = Ll[k+6], o7 = Ll[k+7];
            const float2 a0 = *(const float2*)(lb + o0);
            const float2 a1 = *(const float2*)(lb + o1);
            const float2 a2 = *(const float2*)(lb + o2);
            const float2 a3 = *(const float2*)(lb + o3);
            const float2 a4 = *(const float2*)(lb + o4);
            const float2 a5 = *(const float2*)(lb + o5);
            const float2 a6 = *(const float2*)(lb + o6);
            const float2 a7 = *(const float2*)(lb + o7);
            d0 += a0.x;                         d1 += a0.y;
            d0 += (k+1 < nl) ? a1.x : 0.0f;     d1 += (k+1 < nl) ? a1.y : 0.0f;
            d0 += (k+2 < nl) ? a2.x : 0.0f;     d1 += (k+2 < nl) ? a2.y : 0.0f;
            d0 += (k+3 < nl) ? a3.x : 0.0f;     d1 += (k+3 < nl) ? a3.y : 0.0f;
            d0 += (k+4 < nl) ? a4.x : 0.0f;     d1 += (k+4 < nl) ? a4.y : 0.0f;
            d0 += (k+5 < nl) ? a5.x : 0.0f;     d1 += (k+5 < nl) ? a5.y : 0.0f;
            d0 += (k+6 < nl) ? a6.x : 0.0f;     d1 += (k+6 < nl) ? a6.y : 0.0f;
            d0 += (k+7 < nl) ? a7.x : 0.0f;     d1 += (k+7 < nl) ? a7.y : 0.0f;
        }

        // ---- phase D: HRF update + spikes + stats + list build ----
        hz0 = hz0 + DTC * (d0 - gg.x * hy0 - ee.x * hz0);
        hz1 = hz1 + DTC * (d1 - gg.y * hy1 - ee.y * hz1);
        hy0 = hy0 + DTC * hz0;
        hy1 = hy1 + DTC * hz1;
        const float sn0 = ((hy0 - THETA - rp0) > 0.f) ? 1.f : 0.f;
        const float sn1 = ((hy1 - THETA - rp1) > 0.f) ? 1.f : 0.f;
        rp0 = rp0 * ref_decay + sn0;
        rp1 = rp1 * ref_decay + sn1;
        hysum0 += hy0; hysq0 += hy0 * hy0;
        hysum1 += hy1; hysq1 += hy1 * hy1;
        chrf += (unsigned)sn0 + (unsigned)sn1;
        const unsigned long long sA = __ballot(sn0 > 0.5f);
        const unsigned long long sB = __ballot(sn1 > 0.5f);
        if (lane == 0) Cs[wv] = (int)(__popcll(sA) + __popcll(sB));
        __syncthreads();
        cv = Cs[l8];
        incl = cv;
        #pragma unroll
        for (int d = 1; d < 8; d <<= 1) {
            const int tt = __shfl_up(incl, d, 8);
            incl += (l8 >= d) ? tt : 0;
        }
        ns  = __builtin_amdgcn_readlane(incl, 7);
        pre = __builtin_amdgcn_readlane(incl - cv, wvs);
        {
            const int posA = (int)(__popcll(sA & below) + __popcll(sB & below));
            if (sn0 > 0.5f) Ls[pre + posA] = (unsigned)(u0 * 4096);
            if (sn1 > 0.5f)
                Ls[pre + posA + (int)((sA >> lane) & 1ULL)] = (unsigned)(u0 * 4096 + 4096);
        }
        __syncthreads();
    }

    // ---- epilogue: features (both units; contiguous float2 stores) ----
    const float Lf = (float)LSTEPS;
    float* ob = out + (size_t)b * (3 * NHID);
    {
        const float mean0 = hysum0 / Lf;
        const float mean1 = hysum1 / Lf;
        const float rms0  = sqrtf(hysq0 / Lf + 1e-8f);
        const float rms1  = sqrtf(hysq1 / Lf + 1e-8f);
        float var0 = hysq0 / Lf - mean0 * mean0;
        float var1 = hysq1 / Lf - mean1 * mean1;
        var0 = fmaxf(var0, 1e-8f);
        var1 = fmaxf(var1, 1e-8f);
        *(float2*)(ob + u0)            = make_float2(rms0, rms1);
        *(float2*)(ob + NHID + u0)     = make_float2(sqrtf(var0), sqrtf(var1));
        *(float2*)(ob + 2 * NHID + u0) = make_float2(hy0, hy1);
    }

    // ---- spike-count reduction (exact ints) ----
    unsigned int c = chrf;
    for (int off = 32; off > 0; off >>= 1) c += __shfl_down(c, off, 64);
    if (lane == 0) red[wv] = c;
    __syncthreads();
    if (tid == 0) {
        unsigned int tot = 0;
        for (int i = 0; i < 8; ++i) tot += red[i];
        ws[b * 2] = tot;
    }
    __syncthreads();
    c = clif;
    for (int off = 32; off > 0; off >>= 1) c += __shfl_down(c, off, 64);
    if (lane == 0) red[wv] = c;
    __syncthreads();
    if (tid == 0) {
        unsigned int tot = 0;
        for (int i = 0; i < 8; ++i) tot += red[i];
        ws[b * 2 + 1] = tot;
    }
}

__global__ void coesn_final(const unsigned int* __restrict__ ws,
                            float* __restrict__ out)
{
    if (threadIdx.x == 0 && blockIdx.x == 0) {
        unsigned long long hrf = 0, lif = 0;
        for (int b = 0; b < BATCH; ++b) {
            hrf += ws[b * 2];
            lif += ws[b * 2 + 1];
        }
        const float denom = (float)BATCH * (float)LSTEPS * (float)NHID;
        const float r_hrf = (float)hrf / denom;
        const float r_lif = (float)lif / denom;
        float* s = out + (size_t)BATCH * 3 * NHID;
        s[0] = r_hrf;
        s[1] = r_hrf;
        s[2] = r_lif;
    }
}

extern "C" void kernel_launch(void* const* d_in, const int* in_sizes, int n_in,
                              void* d_out, int out_size, void* d_ws, size_t ws_size,
                              hipStream_t stream) {
    const float* x       = (const float*)d_in[0];
    const float* x2h     = (const float*)d_in[1];
    const float* h2h     = (const float*)d_in[2];
    const float* bias    = (const float*)d_in[3];
    const float* lif2hrf = (const float*)d_in[4];
    const float* gamma_  = (const float*)d_in[5];
    const float* eps_    = (const float*)d_in[6];
    float* out = (float*)d_out;
    unsigned int* wsp = (unsigned int*)d_ws;

    coesn_sim<<<BATCH, NT, 0, stream>>>(x, x2h, h2h, bias, lif2hrf, gamma_, eps_, out, wsp);
    coesn_final<<<1, 64, 0, stream>>>(wsp, out);
}

// Round 12
// 1521.920 us; speedup vs baseline: 1.3481x; 1.1329x over previous
//
#include <hip/hip_runtime.h>

#define NHID    1024
#define BATCH   128
#define LSTEPS  1000
#define DTC     0.042f
#define THETA   1.0f
#define TAUM    20.0f
#define LISTCAP 1040          // multiple of 4 (uint4 reads stay in-bounds)

// One block per batch element; thread h owns hidden unit h (16 waves/CU).
// Binary-spike matmuls = sparse row gathers over a combined LDS offset list
// (ascending j -> f32 add order identical to R1/R3/R9). R12 change vs R9:
// the 8 per-chunk offset reads are 2x ds_read_b128 (uint4) instead of
// 8x ds_read_b32 -- same values, same order, 4x fewer LDS instructions
// (the memory-pipe issue-throughput theory's clean A/B).
__global__ __launch_bounds__(1024) void coesn_sim(
    const float* __restrict__ x,        // (B, L, 1)
    const float* __restrict__ x2h,      // (1, H)
    const float* __restrict__ h2h,      // (H, H)
    const float* __restrict__ bias,     // (H)
    const float* __restrict__ lif2hrf,  // (H, H)
    const float* __restrict__ gamma_,   // (H)
    const float* __restrict__ eps_,     // (H)
    float* __restrict__ out,            // (B, 3H) features
    unsigned int* __restrict__ ws)      // (B, 2) spike counts
{
    const int b    = blockIdx.x;
    const int h    = threadIdx.x;
    const int wv   = h >> 6;
    const int lane = h & 63;
    const int wvs  = __builtin_amdgcn_readfirstlane(wv);

    __shared__ __align__(16) unsigned int Ls[LISTCAP];  // HRF spike row offsets
    __shared__ __align__(16) unsigned int Ll[LISTCAP];  // LIF spike row offsets
    __shared__ int Cs[16], Cl[16];
    __shared__ unsigned int red[16];

    Ls[h] = 0; Ll[h] = 0;                 // stale entries stay in-range forever
    if (h < LISTCAP - 1024) { Ls[1024 + h] = 0; Ll[1024 + h] = 0; }
    if (h < 16) { Cs[h] = 0; Cl[h] = 0; }

    float hy = 0.f, hz = 0.f, v = 0.f, rp = 0.f;
    float hysum = 0.f, hysq = 0.f;
    unsigned int chrf = 0, clif = 0;

    const float g    = gamma_[h];
    const float e    = eps_[h];
    const float bi   = bias[h];
    const float win  = x2h[h];
    const float ref_decay = expf((float)(-0.042 / 0.25));
    const float* xb  = x + (size_t)b * LSTEPS;

    const char* hb = (const char*)h2h     + 4 * (size_t)h;
    const char* lb = (const char*)lif2hrf + 4 * (size_t)h;
    const uint4* Ls4 = (const uint4*)Ls;
    const uint4* Ll4 = (const uint4*)Ll;

    const unsigned long long below = (1ULL << lane) - 1ULL;
    const int l16 = lane & 15;

    int ns = 0;                 // HRF list length (phase A bound); 0 at t=0
    float xv_next = xb[0];      // x prefetch (one step ahead)

    __syncthreads();

    for (int t = 0; t < LSTEPS; ++t) {
        // ---- phase A: cur = x*x2h + bias + sum of spiking h2h rows ----
        const float xv = xv_next;
        xv_next = xb[(t + 1 < LSTEPS) ? (t + 1) : t];
        float cur = xv * win + bi;
        for (int k = 0; k < ns; k += 8) {
            const uint4 q0 = Ls4[(k >> 2)];
            const uint4 q1 = Ls4[(k >> 2) + 1];
            const float a0 = *(const float*)(hb + q0.x);
            const float a1 = *(const float*)(hb + q0.y);
            const float a2 = *(const float*)(hb + q0.z);
            const float a3 = *(const float*)(hb + q0.w);
            const float a4 = *(const float*)(hb + q1.x);
            const float a5 = *(const float*)(hb + q1.y);
            const float a6 = *(const float*)(hb + q1.z);
            const float a7 = *(const float*)(hb + q1.w);
            cur += a0;
            cur += (k+1 < ns) ? a1 : 0.0f;
            cur += (k+2 < ns) ? a2 : 0.0f;
            cur += (k+3 < ns) ? a3 : 0.0f;
            cur += (k+4 < ns) ? a4 : 0.0f;
            cur += (k+5 < ns) ? a5 : 0.0f;
            cur += (k+6 < ns) ? a6 : 0.0f;
            cur += (k+7 < ns) ? a7 : 0.0f;
        }

        // ---- phase B: LIF update + spike + list build ----
        v = v + DTC * (-v / TAUM + cur);
        const float lsp = (v > THETA) ? 1.f : 0.f;
        v -= lsp * THETA;
        clif += (unsigned)lsp;
        const unsigned long long balL = __ballot(lsp > 0.5f);
        if (lane == 0) Cl[wv] = (int)__popcll(balL);
        __syncthreads();
        int cv = Cl[l16];
        int incl = cv;
        #pragma unroll
        for (int d = 1; d < 16; d <<= 1) {
            const int tt = __shfl_up(incl, d, 16);
            incl += (l16 >= d) ? tt : 0;
        }
        int nl  = __builtin_amdgcn_readlane(incl, 15);
        int pre = __builtin_amdgcn_readlane(incl - cv, wvs);
        if (lsp > 0.5f) Ll[pre + (int)__popcll(balL & below)] = (unsigned)(h * 4096);
        __syncthreads();

        // ---- phase C: drive = sum of spiking lif2hrf rows ----
        float dr = 0.f;
        for (int k = 0; k < nl; k += 8) {
            const uint4 q0 = Ll4[(k >> 2)];
            const uint4 q1 = Ll4[(k >> 2) + 1];
            const float a0 = *(const float*)(lb + q0.x);
            const float a1 = *(const float*)(lb + q0.y);
            const float a2 = *(const float*)(lb + q0.z);
            const float a3 = *(const float*)(lb + q0.w);
            const float a4 = *(const float*)(lb + q1.x);
            const float a5 = *(const float*)(lb + q1.y);
            const float a6 = *(const float*)(lb + q1.z);
            const float a7 = *(const float*)(lb + q1.w);
            dr += a0;
            dr += (k+1 < nl) ? a1 : 0.0f;
            dr += (k+2 < nl) ? a2 : 0.0f;
            dr += (k+3 < nl) ? a3 : 0.0f;
            dr += (k+4 < nl) ? a4 : 0.0f;
            dr += (k+5 < nl) ? a5 : 0.0f;
            dr += (k+6 < nl) ? a6 : 0.0f;
            dr += (k+7 < nl) ? a7 : 0.0f;
        }

        // ---- phase D: HRF update + spike + stats + list build ----
        hz = hz + DTC * (dr - g * hy - e * hz);
        hy = hy + DTC * hz;
        const float sn = ((hy - THETA - rp) > 0.f) ? 1.f : 0.f;
        rp = rp * ref_decay + sn;
        hysum += hy;
        hysq  += hy * hy;
        chrf += (unsigned)sn;
        const unsigned long long balS = __ballot(sn > 0.5f);
        if (lane == 0) Cs[wv] = (int)__popcll(balS);
        __syncthreads();
        cv = Cs[l16];
        incl = cv;
        #pragma unroll
        for (int d = 1; d < 16; d <<= 1) {
            const int tt = __shfl_up(incl, d, 16);
            incl += (l16 >= d) ? tt : 0;
        }
        ns  = __builtin_amdgcn_readlane(incl, 15);
        pre = __builtin_amdgcn_readlane(incl - cv, wvs);
        if (sn > 0.5f) Ls[pre + (int)__popcll(balS & below)] = (unsigned)(h * 4096);
        __syncthreads();
    }

    // ---- epilogue: features ----
    const float Lf   = (float)LSTEPS;
    const float mean = hysum / Lf;
    const float rms  = sqrtf(hysq / Lf + 1e-8f);
    float var = hysq / Lf - mean * mean;
    var = fmaxf(var, 1e-8f);
    float* ob = out + (size_t)b * (3 * NHID);
    ob[h]            = rms;
    ob[NHID + h]     = sqrtf(var);
    ob[2 * NHID + h] = hy;

    // ---- spike-count reduction (exact ints) ----
    unsigned int c = chrf;
    for (int off = 32; off > 0; off >>= 1) c += __shfl_down(c, off, 64);
    if (lane == 0) red[wv] = c;
    __syncthreads();
    if (h == 0) {
        unsigned int tot = 0;
        for (int i = 0; i < 16; ++i) tot += red[i];
        ws[b * 2] = tot;
    }
    __syncthreads();
    c = clif;
    for (int off = 32; off > 0; off >>= 1) c += __shfl_down(c, off, 64);
    if (lane == 0) red[wv] = c;
    __syncthreads();
    if (h == 0) {
        unsigned int tot = 0;
        for (int i = 0; i < 16; ++i) tot += red[i];
        ws[b * 2 + 1] = tot;
    }
}

__global__ void coesn_final(const unsigned int* __restrict__ ws,
                            float* __restrict__ out)
{
    if (threadIdx.x == 0 && blockIdx.x == 0) {
        unsigned long long hrf = 0, lif = 0;
        for (int b = 0; b < BATCH; ++b) {
            hrf += ws[b * 2];
            lif += ws[b * 2 + 1];
        }
        const float denom = (float)BATCH * (float)LSTEPS * (float)NHID;
        const float r_hrf = (float)hrf / denom;
        const float r_lif = (float)lif / denom;
        float* s = out + (size_t)BATCH * 3 * NHID;
        s[0] = r_hrf;
        s[1] = r_hrf;
        s[2] = r_lif;
    }
}

extern "C" void kernel_launch(void* const* d_in, const int* in_sizes, int n_in,
                              void* d_out, int out_size, void* d_ws, size_t ws_size,
                              hipStream_t stream) {
    const float* x       = (const float*)d_in[0];
    const float* x2h     = (const float*)d_in[1];
    const float* h2h     = (const float*)d_in[2];
    const float* bias    = (const float*)d_in[3];
    const float* lif2hrf = (const float*)d_in[4];
    const float* gamma_  = (const float*)d_in[5];
    const float* eps_    = (const float*)d_in[6];
    float* out = (float*)d_out;
    unsigned int* wsp = (unsigned int*)d_ws;

    coesn_sim<<<BATCH, NHID, 0, stream>>>(x, x2h, h2h, bias, lif2hrf, gamma_, eps_, out, wsp);
    coesn_final<<<1, 64, 0, stream>>>(wsp, out);
}